// Round 4
// baseline (200.068 us; speedup 1.0000x reference)
//
#include <hip/hip_runtime.h>
#include <math.h>

#define NPTS 131072
#define KCOMP 256
#define DIM 32
#define KF 608                    // 576 quad features (4-aligned rows) + 32 m
#define PSIF_BYTES 311296         // 19456 granules * 16 B
#define WS_NEED (PSIF_BYTES + KCOMP * 4)

typedef __attribute__((ext_vector_type(8))) short short8;
typedef __attribute__((ext_vector_type(16))) float f32x16;

__device__ __forceinline__ unsigned short f2bf(float v) {
    unsigned u = __float_as_uint(v);
    u += 0x7fffu + ((u >> 16) & 1u);   // RNE
    return (unsigned short)(u >> 16);
}

// pack two f32 -> two bf16 (lo | hi<<16). RTN (+0x8000) + byte-perm: 3 ops.
__device__ __forceinline__ unsigned pkbf(float lo, float hi) {
#if __has_builtin(__builtin_amdgcn_perm)
    const unsigned a = __float_as_uint(hi) + 0x8000u;   // bytes 4..7 of pool
    const unsigned b = __float_as_uint(lo) + 0x8000u;   // bytes 0..3 of pool
    return __builtin_amdgcn_perm(a, b, 0x07060302u);    // [b2,b3,a2,a3]
#else
    return (unsigned)f2bf(lo) | ((unsigned)f2bf(hi) << 16);
#endif
}

// ---- compile-time feature decode: quad-packed triangular, 4-aligned rows ----
constexpr int L4c(int d) { return ((32 - d + 3) / 4) * 4; }
constexpr int PfxC(int d) { int s = 0; for (int i = 0; i < d; ++i) s += L4c(i); return s; }
constexpr int rowOfC(int p) { int d = 0; while (d < 31 && PfxC(d + 1) <= p) ++d; return d; }
constexpr int dOfC(int p) { return (p >= 576) ? -1 : rowOfC(p); }
constexpr int f0OfC(int p) {
    return (p >= 576) ? (p - 576) : ((rowOfC(p) & ~3) + (p - PfxC(rowOfC(p))));
}

// ---------------------------------------------------------------------------
// Precompute: Psi column k scattered into frag-ordered PsiF (bf16), kc2 fp32.
// ---------------------------------------------------------------------------
__global__ __launch_bounds__(256) void gmm_pre(
    const float* __restrict__ S,
    const float* __restrict__ centers,
    const float* __restrict__ weights,
    unsigned short* __restrict__ PsiF,
    float* __restrict__ kc2)
{
    __shared__ float Sl[DIM][DIM + 1];
    __shared__ float As[DIM][DIM + 1];
    __shared__ float cl[DIM], ml[DIM];
    __shared__ float red[256];

    const int k = blockIdx.x, tid = threadIdx.x;

    for (int idx = tid; idx < DIM * DIM; idx += 256)
        Sl[idx >> 5][idx & 31] = S[(size_t)k * DIM * DIM + idx];
    if (tid < DIM) cl[tid] = centers[k * DIM + tid];
    __syncthreads();

    // A = S S^T
    for (int idx = tid; idx < DIM * DIM; idx += 256) {
        const int d = idx >> 5, f = idx & 31;
        float a = 0.f;
#pragma unroll
        for (int e = 0; e < DIM; ++e) a = fmaf(Sl[d][e], Sl[f][e], a);
        As[d][f] = a;
    }
    __syncthreads();

    if (tid < DIM) {
        float mv = 0.f;
#pragma unroll
        for (int f = 0; f < DIM; ++f) mv = fmaf(As[tid][f], cl[f], mv);
        ml[tid] = mv;
    }
    __syncthreads();

    // scatter Psi column k into frag positions (reads As diag+upper, ml)
    for (int p = tid; p < KF; p += 256) {
        float val;
        if (p < 576) {
            int d = 0, pr = 0;
            while (true) {
                const int len = ((32 - d + 3) >> 2) << 2;
                if (pr + len > p) break;
                pr += len; ++d;
            }
            const int f = (d & ~3) + (p - pr);
            val = (f < d) ? 0.f : ((f == d) ? -0.5f * As[d][d] : -As[d][f]);
        } else {
            val = ml[p - 576];
        }
        const int c = p >> 6, kk = p & 63;
        const int s = kk >> 4, qq = (kk >> 3) & 1, j = kk & 7;
        const int ct = k >> 5, ll = qq * 32 + (k & 31);
        const int g = c * 2048 + (s * 8 + ct) * 64 + ll;
        PsiF[(size_t)g * 8 + j] = f2bf(val);
    }

    red[tid] = fabsf(weights[tid]);          // K == 256 == blockDim
    __syncthreads();                          // also fences As/ml reads above
    for (int off = 128; off > 0; off >>= 1) {
        if (tid < off) red[tid] += red[tid + off];
        __syncthreads();
    }
    const float wsum = red[0];

    // SPD Gaussian elimination: 1 barrier/step, logdet(A) = sum log(pivot_j).
    // Step j writes only (r>j, c>j); reads row j and col j -> untouched. Safe.
    for (int j = 0; j < DIM - 1; ++j) {
        const float inv = 1.0f / As[j][j];
        for (int idx = tid; idx < DIM * DIM; idx += 256) {
            const int r = idx >> 5, c = idx & 31;
            if (r > j && c > j)
                As[r][c] = fmaf(-As[r][j] * inv, As[j][c], As[r][c]);
        }
        __syncthreads();
    }

    if (tid < DIM) red[tid] = __logf(As[tid][tid]);   // pivots > 0 (SPD)
    __syncthreads();
    if (tid == 0) {
        float sl = 0.f;
        for (int j = 0; j < DIM; ++j) sl += red[j];
        float cac = 0.f;
        for (int d2 = 0; d2 < DIM; ++d2) cac = fmaf(ml[d2], cl[d2], cac);
        kc2[k] = __logf(fabsf(weights[k])) - __logf(wsum + 1e-30f)
               + 0.5f * sl - 0.5f * cac;
    }
}

// ---------------------------------------------------------------------------
// Main MFMA kernel (software-pipelined: B prefetched to registers)
// ---------------------------------------------------------------------------
template<int P>
__device__ __forceinline__ void genQuad(const float (&x)[DIM], float* v) {
    constexpr int d = dOfC(P);
    constexpr int f0 = f0OfC(P);
#pragma unroll
    for (int j = 0; j < 4; ++j)
        v[j] = (d < 0) ? x[f0 + j] : (x[d] * x[f0 + j]);
}

template<int C, int SS>
__device__ __forceinline__ void genSite(const float (&x)[DIM], uint4* sA4,
                                        int rbg, int r32) {
    float v[8];
    genQuad<C * 64 + SS * 8>(x, v);
    genQuad<C * 64 + SS * 8 + 4>(x, v + 4);
    uint4 u;
    u.x = pkbf(v[0], v[1]);
    u.y = pkbf(v[2], v[3]);
    u.z = pkbf(v[4], v[5]);
    u.w = pkbf(v[6], v[7]);
    sA4[(SS >> 1) * 256 + rbg * 64 + (SS & 1) * 32 + r32] = u;
}

template<int C>
__device__ __forceinline__ void doChunk(const float (&x)[DIM],
    uint4* sA4, uint4* sB4, const uint4* __restrict__ PsiF4,
    f32x16 (&acc0)[4], f32x16 (&acc1)[4], uint4 (&regB)[8],
    int t, int l, int q, int rbg, int r32, int r0, int c0)
{
    constexpr int NS  = (C < 9) ? 4 : 2;                   // K16-steps here
    constexpr int NSn = (C < 8) ? 4 : ((C == 8) ? 2 : 0);  // next chunk's

    __syncthreads();   // previous chunk's LDS reads complete
    if (q == 0) {
        genSite<C, 0>(x, sA4, rbg, r32);
        genSite<C, 2>(x, sA4, rbg, r32);
        if constexpr (NS == 4) { genSite<C, 4>(x, sA4, rbg, r32); genSite<C, 6>(x, sA4, rbg, r32); }
    } else {
        genSite<C, 1>(x, sA4, rbg, r32);
        genSite<C, 3>(x, sA4, rbg, r32);
        if constexpr (NS == 4) { genSite<C, 5>(x, sA4, rbg, r32); genSite<C, 7>(x, sA4, rbg, r32); }
    }
#pragma unroll
    for (int m = 0; m < NS * 2; ++m) sB4[m * 256 + t] = regB[m];
    __syncthreads();

    // prefetch next chunk's B into registers; consumed next iteration, so the
    // vmcnt wait lands after a full MFMA phase (~1k cyc) of cover.
    if constexpr (NSn > 0) {
        const uint4* srcn = PsiF4 + (C + 1) * 2048;
#pragma unroll
        for (int m = 0; m < NSn * 2; ++m) regB[m] = srcn[m * 256 + t];
    }

#pragma unroll
    for (int s = 0; s < NS; ++s) {
        short8 a0 = __builtin_bit_cast(short8, sA4[(s * 4 + r0) * 64 + l]);
        short8 a1 = __builtin_bit_cast(short8, sA4[(s * 4 + r0 + 1) * 64 + l]);
#pragma unroll
        for (int j = 0; j < 4; ++j) {
            short8 b = __builtin_bit_cast(short8, sB4[(s * 8 + c0 + j) * 64 + l]);
            acc0[j] = __builtin_amdgcn_mfma_f32_32x32x16_bf16(a0, b, acc0[j], 0, 0, 0);
            acc1[j] = __builtin_amdgcn_mfma_f32_32x32x16_bf16(a1, b, acc1[j], 0, 0, 0);
        }
    }
}

__device__ __forceinline__ void epiHalf(const f32x16 (&acc)[4], const float (&kcv)[4],
    int rblock, int l, int whalf, float (*sM)[2], float (*sS)[2])
{
#pragma unroll
    for (int rg = 0; rg < 16; ++rg) {
        float vals[4], m = -INFINITY;
#pragma unroll
        for (int j = 0; j < 4; ++j) { vals[j] = acc[j][rg] + kcv[j]; m = fmaxf(m, vals[j]); }
#pragma unroll
        for (int mask = 1; mask < 32; mask <<= 1) m = fmaxf(m, __shfl_xor(m, mask, 64));
        float sv = 0.f;
#pragma unroll
        for (int j = 0; j < 4; ++j) sv += __expf(vals[j] - m);
#pragma unroll
        for (int mask = 1; mask < 32; mask <<= 1) sv += __shfl_xor(sv, mask, 64);
        if ((l & 31) == 0) {
            const int R = rblock * 32 + (rg & 3) + 8 * (rg >> 2) + 4 * (l >> 5);
            sM[R][whalf] = m; sS[R][whalf] = sv;
        }
    }
}

__global__ __launch_bounds__(256, 2) void gmm_mfma(
    const float* __restrict__ points,
    const unsigned short* __restrict__ PsiF,
    const float* __restrict__ kc2,
    const float* __restrict__ thr,
    float* __restrict__ out)
{
    __shared__ uint4 sA4[1024];          // 16 KB: 128 rows x 64 k, frag order
    __shared__ uint4 sB4[2048];          // 32 KB: 64 k x 256 cols, frag order
    __shared__ float sM[128][2], sS[128][2];

    const int t = threadIdx.x;
    const int w = t >> 6, l = t & 63;
    const int row = t & 127, q = t >> 7;           // gen role: 2 threads/row
    const int rbg = row >> 5, r32 = row & 31;
    const int r0 = (w >> 1) * 2, c0 = (w & 1) * 4; // mfma wave tile: 64r x 128c

    const uint4* PsiF4 = (const uint4*)PsiF;
    uint4 regB[8];
#pragma unroll
    for (int m = 0; m < 8; ++m) regB[m] = PsiF4[m * 256 + t];   // chunk 0

    float x[DIM];
    const float4* px = (const float4*)(points + ((size_t)blockIdx.x * 128 + row) * DIM);
#pragma unroll
    for (int j2 = 0; j2 < 8; ++j2) {
        float4 v = px[j2];
        x[4 * j2 + 0] = v.x; x[4 * j2 + 1] = v.y;
        x[4 * j2 + 2] = v.z; x[4 * j2 + 3] = v.w;
    }

    f32x16 acc0[4], acc1[4];
#pragma unroll
    for (int j = 0; j < 4; ++j)
#pragma unroll
        for (int r = 0; r < 16; ++r) { acc0[j][r] = 0.f; acc1[j][r] = 0.f; }

    doChunk<0>(x, sA4, sB4, PsiF4, acc0, acc1, regB, t, l, q, rbg, r32, r0, c0);
    doChunk<1>(x, sA4, sB4, PsiF4, acc0, acc1, regB, t, l, q, rbg, r32, r0, c0);
    doChunk<2>(x, sA4, sB4, PsiF4, acc0, acc1, regB, t, l, q, rbg, r32, r0, c0);
    doChunk<3>(x, sA4, sB4, PsiF4, acc0, acc1, regB, t, l, q, rbg, r32, r0, c0);
    doChunk<4>(x, sA4, sB4, PsiF4, acc0, acc1, regB, t, l, q, rbg, r32, r0, c0);
    doChunk<5>(x, sA4, sB4, PsiF4, acc0, acc1, regB, t, l, q, rbg, r32, r0, c0);
    doChunk<6>(x, sA4, sB4, PsiF4, acc0, acc1, regB, t, l, q, rbg, r32, r0, c0);
    doChunk<7>(x, sA4, sB4, PsiF4, acc0, acc1, regB, t, l, q, rbg, r32, r0, c0);
    doChunk<8>(x, sA4, sB4, PsiF4, acc0, acc1, regB, t, l, q, rbg, r32, r0, c0);
    doChunk<9>(x, sA4, sB4, PsiF4, acc0, acc1, regB, t, l, q, rbg, r32, r0, c0);

    // epilogue: add kc2, row-wise LSE over 256 cols (two 128-col halves)
    float kcv[4];
#pragma unroll
    for (int j = 0; j < 4; ++j) kcv[j] = kc2[(c0 + j) * 32 + (l & 31)];

    epiHalf(acc0, kcv, r0,     l, w & 1, sM, sS);
    epiHalf(acc1, kcv, r0 + 1, l, w & 1, sM, sS);
    __syncthreads();

    if (t < 128) {
        const float m0 = sM[t][0], m1 = sM[t][1];
        const float M = fmaxf(m0, m1);
        const float Sv = sS[t][0] * __expf(m0 - M) + sS[t][1] * __expf(m1 - M);
        out[(size_t)blockIdx.x * 128 + t] = M + __logf(Sv) - thr[0];
    }
}

extern "C" void kernel_launch(void* const* d_in, const int* in_sizes, int n_in,
                              void* d_out, int out_size, void* d_ws, size_t ws_size,
                              hipStream_t stream) {
    const float* points  = (const float*)d_in[0];
    const float* centers = (const float*)d_in[1];
    const float* covs    = (const float*)d_in[2];
    const float* weights = (const float*)d_in[3];
    const float* thr     = (const float*)d_in[4];
    float* out = (float*)d_out;

    unsigned short* PsiF = (unsigned short*)d_ws;
    float* kc2 = (float*)((char*)d_ws + PSIF_BYTES);

    gmm_pre<<<KCOMP, 256, 0, stream>>>(covs, centers, weights, PsiF, kc2);
    gmm_mfma<<<NPTS / 128, 256, 0, stream>>>(points, PsiF, kc2, thr, out);
}

// Round 5
// 150.442 us; speedup vs baseline: 1.3299x; 1.3299x over previous
//
#include <hip/hip_runtime.h>
#include <math.h>

#define NPTS 131072
#define KCOMP 256
#define DIM 32
#define KF 608                    // 576 quad features (4-aligned rows) + 32 m
#define PSIF_BYTES 311296         // 19456 granules * 16 B
#define WS_NEED (PSIF_BYTES + KCOMP * 4)

typedef __attribute__((ext_vector_type(8))) short short8;
typedef __attribute__((ext_vector_type(16))) float f32x16;

__device__ __forceinline__ unsigned short f2bf(float v) {
    unsigned u = __float_as_uint(v);
    u += 0x7fffu + ((u >> 16) & 1u);   // RNE
    return (unsigned short)(u >> 16);
}

// pack two f32 -> two bf16 (lo | hi<<16). RTN (+0x8000) + byte-perm: 3 ops.
__device__ __forceinline__ unsigned pkbf(float lo, float hi) {
#if __has_builtin(__builtin_amdgcn_perm)
    const unsigned a = __float_as_uint(hi) + 0x8000u;
    const unsigned b = __float_as_uint(lo) + 0x8000u;
    return __builtin_amdgcn_perm(a, b, 0x07060302u);
#else
    return (unsigned)f2bf(lo) | ((unsigned)f2bf(hi) << 16);
#endif
}

// async global->LDS DMA, 16 B/lane; LDS dest = wave-uniform base + lane*16.
__device__ __forceinline__ void dma16(const uint4* g, uint4* s) {
    __builtin_amdgcn_global_load_lds(
        (const __attribute__((address_space(1))) void*)g,
        (__attribute__((address_space(3))) void*)s, 16, 0, 0);
}

// LDS-only barrier: drain lgkmcnt but let global_load_lds (vmcnt) keep flying.
__device__ __forceinline__ void barrier_lds_only() {
    asm volatile("s_waitcnt lgkmcnt(0)\ns_barrier" ::: "memory");
}

// ---- compile-time feature decode: quad-packed triangular, 4-aligned rows ----
constexpr int L4c(int d) { return ((32 - d + 3) / 4) * 4; }
constexpr int PfxC(int d) { int s = 0; for (int i = 0; i < d; ++i) s += L4c(i); return s; }
constexpr int rowOfC(int p) { int d = 0; while (d < 31 && PfxC(d + 1) <= p) ++d; return d; }
constexpr int dOfC(int p) { return (p >= 576) ? -1 : rowOfC(p); }
constexpr int f0OfC(int p) {
    return (p >= 576) ? (p - 576) : ((rowOfC(p) & ~3) + (p - PfxC(rowOfC(p))));
}

// ---------------------------------------------------------------------------
// Precompute: Psi column k scattered into frag-ordered PsiF (bf16), kc2 fp32.
// ---------------------------------------------------------------------------
__global__ __launch_bounds__(256) void gmm_pre(
    const float* __restrict__ S,
    const float* __restrict__ centers,
    const float* __restrict__ weights,
    unsigned short* __restrict__ PsiF,
    float* __restrict__ kc2)
{
    __shared__ float Sl[DIM][DIM + 1];
    __shared__ float As[DIM][DIM + 1];
    __shared__ float cl[DIM], ml[DIM];
    __shared__ float red[256];

    const int k = blockIdx.x, tid = threadIdx.x;

    for (int idx = tid; idx < DIM * DIM; idx += 256)
        Sl[idx >> 5][idx & 31] = S[(size_t)k * DIM * DIM + idx];
    if (tid < DIM) cl[tid] = centers[k * DIM + tid];
    __syncthreads();

    // A = S S^T
    for (int idx = tid; idx < DIM * DIM; idx += 256) {
        const int d = idx >> 5, f = idx & 31;
        float a = 0.f;
#pragma unroll
        for (int e = 0; e < DIM; ++e) a = fmaf(Sl[d][e], Sl[f][e], a);
        As[d][f] = a;
    }
    __syncthreads();

    if (tid < DIM) {
        float mv = 0.f;
#pragma unroll
        for (int f = 0; f < DIM; ++f) mv = fmaf(As[tid][f], cl[f], mv);
        ml[tid] = mv;
    }
    __syncthreads();

    // scatter Psi column k into frag positions (reads As diag+upper, ml)
    for (int p = tid; p < KF; p += 256) {
        float val;
        if (p < 576) {
            int d = 0, pr = 0;
            while (true) {
                const int len = ((32 - d + 3) >> 2) << 2;
                if (pr + len > p) break;
                pr += len; ++d;
            }
            const int f = (d & ~3) + (p - pr);
            val = (f < d) ? 0.f : ((f == d) ? -0.5f * As[d][d] : -As[d][f]);
        } else {
            val = ml[p - 576];
        }
        const int c = p >> 6, kk = p & 63;
        const int s = kk >> 4, qq = (kk >> 3) & 1, j = kk & 7;
        const int ct = k >> 5, ll = qq * 32 + (k & 31);
        const int g = c * 2048 + (s * 8 + ct) * 64 + ll;
        PsiF[(size_t)g * 8 + j] = f2bf(val);
    }

    red[tid] = fabsf(weights[tid]);          // K == 256 == blockDim
    __syncthreads();                          // also fences As/ml reads above
    for (int off = 128; off > 0; off >>= 1) {
        if (tid < off) red[tid] += red[tid + off];
        __syncthreads();
    }
    const float wsum = red[0];

    // SPD Gaussian elimination: 1 barrier/step, logdet(A) = sum log(pivot_j).
    for (int j = 0; j < DIM - 1; ++j) {
        const float inv = 1.0f / As[j][j];
        for (int idx = tid; idx < DIM * DIM; idx += 256) {
            const int r = idx >> 5, c = idx & 31;
            if (r > j && c > j)
                As[r][c] = fmaf(-As[r][j] * inv, As[j][c], As[r][c]);
        }
        __syncthreads();
    }

    if (tid < DIM) red[tid] = __logf(As[tid][tid]);   // pivots > 0 (SPD)
    __syncthreads();
    if (tid == 0) {
        float sl = 0.f;
        for (int j = 0; j < DIM; ++j) sl += red[j];
        float cac = 0.f;
        for (int d2 = 0; d2 < DIM; ++d2) cac = fmaf(ml[d2], cl[d2], cac);
        kc2[k] = __logf(fabsf(weights[k])) - __logf(wsum + 1e-30f)
               + 0.5f * sl - 0.5f * cac;
    }
}

// ---------------------------------------------------------------------------
// Main MFMA kernel: A genned in LDS, B DMA'd double-buffered via
// global_load_lds (zero VGPR staging), 1 lgkm-only + 1 full barrier per chunk.
// ---------------------------------------------------------------------------
template<int P>
__device__ __forceinline__ void genQuad(const float (&x)[DIM], float* v) {
    constexpr int d = dOfC(P);
    constexpr int f0 = f0OfC(P);
#pragma unroll
    for (int j = 0; j < 4; ++j)
        v[j] = (d < 0) ? x[f0 + j] : (x[d] * x[f0 + j]);
}

template<int C, int SS>
__device__ __forceinline__ void genSite(const float (&x)[DIM], uint4* sA4,
                                        int rbg, int r32) {
    float v[8];
    genQuad<C * 64 + SS * 8>(x, v);
    genQuad<C * 64 + SS * 8 + 4>(x, v + 4);
    uint4 u;
    u.x = pkbf(v[0], v[1]);
    u.y = pkbf(v[2], v[3]);
    u.z = pkbf(v[4], v[5]);
    u.w = pkbf(v[6], v[7]);
    sA4[(SS >> 1) * 256 + rbg * 64 + (SS & 1) * 32 + r32] = u;
}

template<int C>
__device__ __forceinline__ void doChunk(const float (&x)[DIM],
    uint4* sA4, uint4* sB4, const uint4* __restrict__ PsiF4,
    f32x16 (&acc0)[4], f32x16 (&acc1)[4],
    int l, int w, int q, int rbg, int r32, int r0, int c0)
{
    constexpr int NS  = (C < 9) ? 4 : 2;                   // K16-steps here
    constexpr int NSn = (C < 8) ? 4 : ((C == 8) ? 2 : 0);  // next chunk's

    if constexpr (C > 0) barrier_lds_only();   // sA(c-1)/buf[(c-1)&1] readers done
    // gen A(c) -> sA
    if (q == 0) {
        genSite<C, 0>(x, sA4, rbg, r32);
        genSite<C, 2>(x, sA4, rbg, r32);
        if constexpr (NS == 4) { genSite<C, 4>(x, sA4, rbg, r32); genSite<C, 6>(x, sA4, rbg, r32); }
    } else {
        genSite<C, 1>(x, sA4, rbg, r32);
        genSite<C, 3>(x, sA4, rbg, r32);
        if constexpr (NS == 4) { genSite<C, 5>(x, sA4, rbg, r32); genSite<C, 7>(x, sA4, rbg, r32); }
    }
    __syncthreads();   // sA ready; drains DMA(c) (issued a full chunk ago)

    // issue DMA for chunk c+1 into the other buffer; drained at next full
    // barrier with MFMA(c)+gen(c+1) of cover.
    if constexpr (NSn > 0) {
        const uint4* src = PsiF4 + (C + 1) * 2048 + w * 64 + l;
        uint4* dst = sB4 + ((C + 1) & 1) * 2048 + w * 64 + l;
#pragma unroll
        for (int i = 0; i < NSn * 2; ++i) dma16(src + i * 256, dst + i * 256);
    }

    const uint4* bb = sB4 + (C & 1) * 2048;
#pragma unroll
    for (int s = 0; s < NS; ++s) {
        short8 a0 = __builtin_bit_cast(short8, sA4[(s * 4 + r0) * 64 + l]);
        short8 a1 = __builtin_bit_cast(short8, sA4[(s * 4 + r0 + 1) * 64 + l]);
#pragma unroll
        for (int j = 0; j < 4; ++j) {
            short8 b = __builtin_bit_cast(short8, bb[(s * 8 + c0 + j) * 64 + l]);
            acc0[j] = __builtin_amdgcn_mfma_f32_32x32x16_bf16(a0, b, acc0[j], 0, 0, 0);
            acc1[j] = __builtin_amdgcn_mfma_f32_32x32x16_bf16(a1, b, acc1[j], 0, 0, 0);
        }
    }
}

__device__ __forceinline__ void epiHalf(const f32x16 (&acc)[4], const float (&kcv)[4],
    int rblock, int l, int whalf, float (*sM)[2], float (*sS)[2])
{
#pragma unroll
    for (int rg = 0; rg < 16; ++rg) {
        float vals[4], m = -INFINITY;
#pragma unroll
        for (int j = 0; j < 4; ++j) { vals[j] = acc[j][rg] + kcv[j]; m = fmaxf(m, vals[j]); }
#pragma unroll
        for (int mask = 1; mask < 32; mask <<= 1) m = fmaxf(m, __shfl_xor(m, mask, 64));
        float sv = 0.f;
#pragma unroll
        for (int j = 0; j < 4; ++j) sv += __expf(vals[j] - m);
#pragma unroll
        for (int mask = 1; mask < 32; mask <<= 1) sv += __shfl_xor(sv, mask, 64);
        if ((l & 31) == 0) {
            const int R = rblock * 32 + (rg & 3) + 8 * (rg >> 2) + 4 * (l >> 5);
            sM[R][whalf] = m; sS[R][whalf] = sv;
        }
    }
}

__global__ __launch_bounds__(256, 2) void gmm_mfma(
    const float* __restrict__ points,
    const unsigned short* __restrict__ PsiF,
    const float* __restrict__ kc2,
    const float* __restrict__ thr,
    float* __restrict__ out)
{
    __shared__ uint4 sA4[1024];          // 16 KB: frag-ordered A chunk
    __shared__ uint4 sB4[4096];          // 64 KB: B double buffer (2 x 32 KB)
    // epilogue scratch overlaid on sA4 (after a barrier): sM 1 KB, sS 1 KB
    float (*sM)[2] = (float (*)[2])sA4;
    float (*sS)[2] = (float (*)[2])(sA4 + 64);

    const int t = threadIdx.x;
    const int w = t >> 6, l = t & 63;
    const int row = t & 127, q = t >> 7;           // gen role: 2 threads/row
    const int rbg = row >> 5, r32 = row & 31;
    const int r0 = (w >> 1) * 2, c0 = (w & 1) * 4; // mfma wave tile: 64r x 128c

    const uint4* PsiF4 = (const uint4*)PsiF;

    // prologue DMA: chunk 0's B into buffer 0 (covered by x-load + init + gen)
    {
        const uint4* src = PsiF4 + w * 64 + l;
        uint4* dst = sB4 + w * 64 + l;
#pragma unroll
        for (int i = 0; i < 8; ++i) dma16(src + i * 256, dst + i * 256);
    }

    float x[DIM];
    const float4* px = (const float4*)(points + ((size_t)blockIdx.x * 128 + row) * DIM);
#pragma unroll
    for (int j2 = 0; j2 < 8; ++j2) {
        float4 v = px[j2];
        x[4 * j2 + 0] = v.x; x[4 * j2 + 1] = v.y;
        x[4 * j2 + 2] = v.z; x[4 * j2 + 3] = v.w;
    }

    f32x16 acc0[4], acc1[4];
#pragma unroll
    for (int j = 0; j < 4; ++j)
#pragma unroll
        for (int r = 0; r < 16; ++r) { acc0[j][r] = 0.f; acc1[j][r] = 0.f; }

    doChunk<0>(x, sA4, sB4, PsiF4, acc0, acc1, l, w, q, rbg, r32, r0, c0);
    doChunk<1>(x, sA4, sB4, PsiF4, acc0, acc1, l, w, q, rbg, r32, r0, c0);
    doChunk<2>(x, sA4, sB4, PsiF4, acc0, acc1, l, w, q, rbg, r32, r0, c0);
    doChunk<3>(x, sA4, sB4, PsiF4, acc0, acc1, l, w, q, rbg, r32, r0, c0);
    doChunk<4>(x, sA4, sB4, PsiF4, acc0, acc1, l, w, q, rbg, r32, r0, c0);
    doChunk<5>(x, sA4, sB4, PsiF4, acc0, acc1, l, w, q, rbg, r32, r0, c0);
    doChunk<6>(x, sA4, sB4, PsiF4, acc0, acc1, l, w, q, rbg, r32, r0, c0);
    doChunk<7>(x, sA4, sB4, PsiF4, acc0, acc1, l, w, q, rbg, r32, r0, c0);
    doChunk<8>(x, sA4, sB4, PsiF4, acc0, acc1, l, w, q, rbg, r32, r0, c0);
    doChunk<9>(x, sA4, sB4, PsiF4, acc0, acc1, l, w, q, rbg, r32, r0, c0);

    // epilogue: add kc2, row-wise LSE over 256 cols (two 128-col halves)
    float kcv[4];
#pragma unroll
    for (int j = 0; j < 4; ++j) kcv[j] = kc2[(c0 + j) * 32 + (l & 31)];

    __syncthreads();                       // all sA readers done before overlay
    epiHalf(acc0, kcv, r0,     l, w & 1, sM, sS);
    epiHalf(acc1, kcv, r0 + 1, l, w & 1, sM, sS);
    __syncthreads();

    if (t < 128) {
        const float m0 = sM[t][0], m1 = sM[t][1];
        const float M = fmaxf(m0, m1);
        const float Sv = sS[t][0] * __expf(m0 - M) + sS[t][1] * __expf(m1 - M);
        out[(size_t)blockIdx.x * 128 + t] = M + __logf(Sv) - thr[0];
    }
}

extern "C" void kernel_launch(void* const* d_in, const int* in_sizes, int n_in,
                              void* d_out, int out_size, void* d_ws, size_t ws_size,
                              hipStream_t stream) {
    const float* points  = (const float*)d_in[0];
    const float* centers = (const float*)d_in[1];
    const float* covs    = (const float*)d_in[2];
    const float* weights = (const float*)d_in[3];
    const float* thr     = (const float*)d_in[4];
    float* out = (float*)d_out;

    unsigned short* PsiF = (unsigned short*)d_ws;
    float* kc2 = (float*)((char*)d_ws + PSIF_BYTES);

    gmm_pre<<<KCOMP, 256, 0, stream>>>(covs, centers, weights, PsiF, kc2);
    gmm_mfma<<<NPTS / 128, 256, 0, stream>>>(points, PsiF, kc2, thr, out);
}